// Round 7
// baseline (13063.605 us; speedup 1.0000x reference)
//
#include <hip/hip_runtime.h>

// Problem constants
constexpr int BB = 128;   // batch
constexpr int TPp = 128;  // premise len
constexpr int THh = 64;   // hypothesis len
constexpr int HH = 512;   // hidden

// ---------------- workspace layout (fp32 words) ----------------
constexpr size_t OFF_HS     = 0;                               // premise h history [b][t][512]
constexpr size_t SZ_HS      = (size_t)16384 * 512;
constexpr size_t OFF_HT     = OFF_HS + SZ_HS;                  // hyp h history [b][t][512]
constexpr size_t SZ_HT      = (size_t)8192 * 512;
constexpr size_t OFF_WSM    = OFF_HT + SZ_HT;                  // Ws (match) / LSTM domain xg [16dom][16t][16b][2048c]
constexpr size_t SZ_WSM     = (size_t)16384 * 512;
constexpr size_t OFF_WIHT_P = OFF_WSM + SZ_WSM;                // [304 k][2048 col] rows 300-302 zero, 303=bih+bhh
constexpr size_t SZ_WIHT    = (size_t)304 * 2048;
constexpr size_t OFF_WIHT_H = OFF_WIHT_P + SZ_WIHT;
constexpr size_t OFF_WHHT_P = OFF_WIHT_H + SZ_WIHT;            // WL_P [2048 c][512 k], c=j*4+g
constexpr size_t OFF_WHHT_H = OFF_WHHT_P + (size_t)512 * 2048; // WL_H
constexpr size_t OFF_WB1T   = OFF_WHHT_H + (size_t)512 * 2048; // [2560 c][1024 k]
constexpr size_t OFF_WIA    = OFF_WB1T + (size_t)2560 * 1024;  // WIAT [2048 c][512 k], c=j*4+g
constexpr size_t OFF_WEF    = OFF_WIA + (size_t)2048 * 512;    // w_e [512]
constexpr size_t OFF_BM     = OFF_WEF + 512;                   // bih_m+bhh_m [2048]
constexpr size_t OFF_HC_P   = OFF_BM + 2048;                   // 2 x [128][512] h carry dbuf (premise)
constexpr size_t OFF_HC_H   = OFF_HC_P + 2 * (size_t)BB * HH;  // 2 x [128][512] (hyp)
constexpr size_t OFF_C_P    = OFF_HC_H + 2 * (size_t)BB * HH;  // vestigial (zeroed)
constexpr size_t OFF_C_H    = OFF_C_P + (size_t)BB * HH;
constexpr size_t OFF_Q      = OFF_C_H + (size_t)BB * HH;       // q [128 r][512 c]
constexpr size_t OFF_GH     = OFF_Q + (size_t)BB * HH;         // gh [128 r][2048 c], c=j*4+g
constexpr size_t OFF_A      = OFF_GH + (size_t)BB * 2048;      // abuf [128 b][512 j]
constexpr size_t OFF_HM     = OFF_A + (size_t)BB * HH;         // hm [128 r][512 j]
constexpr size_t OFF_CM     = OFF_HM + (size_t)BB * HH;        // vestigial (zeroed)
constexpr size_t OFF_LAST   = OFF_CM + (size_t)BB * HH;        // [128 r][512 j]
constexpr size_t OFF_BARP   = OFF_LAST + (size_t)BB * HH;      // premise domain barriers: 8 doms x 17 slots x 16
constexpr size_t OFF_BARH   = OFF_BARP + 2560;                 // hyp domain barriers
constexpr size_t OFF_BARF   = OFF_BARH + 2560;                 // unused (zeroed)
constexpr size_t OFF_BARM   = OFF_BARF + 4352;                 // match domain barriers: 8 doms x 33 slots x 16
constexpr size_t WS_FLOATS  = OFF_BARM + 4352;

__device__ __forceinline__ float sigmf(float x) { return 1.0f / (1.0f + __expf(-x)); }
__device__ __forceinline__ float tanh_f(float x) {
  float e = __expf(-2.0f * fabsf(x));
  float r = (1.0f - e) / (1.0f + e);
  return copysignf(r, x);
}

// ---- device-coherent (sc0 sc1) access: serviced at coherence point, never stale-cached ----
__device__ __forceinline__ float aload4(const float* p) {
  unsigned u = __hip_atomic_load((const unsigned*)p, __ATOMIC_RELAXED, __HIP_MEMORY_SCOPE_AGENT);
  return __uint_as_float(u);
}
__device__ __forceinline__ void astore4(float* p, float v) {
  __hip_atomic_store((unsigned*)p, __float_as_uint(v), __ATOMIC_RELAXED, __HIP_MEMORY_SCOPE_AGENT);
}
__device__ __forceinline__ float4 aload16(const float* p) {
  const unsigned long long* q = (const unsigned long long*)p;
  unsigned long long u0 = __hip_atomic_load(q, __ATOMIC_RELAXED, __HIP_MEMORY_SCOPE_AGENT);
  unsigned long long u1 = __hip_atomic_load(q + 1, __ATOMIC_RELAXED, __HIP_MEMORY_SCOPE_AGENT);
  union { unsigned long long u; float2 f; } c0, c1;
  c0.u = u0; c1.u = u1;
  float4 f; f.x = c0.f.x; f.y = c0.f.y; f.z = c1.f.x; f.w = c1.f.y;
  return f;
}
__device__ __forceinline__ void astore16(float* p, float4 v) {
  union { unsigned long long u; float2 f; } c0, c1;
  c0.f.x = v.x; c0.f.y = v.y; c1.f.x = v.z; c1.f.y = v.w;
  unsigned long long* q = (unsigned long long*)p;
  __hip_atomic_store(q, c0.u, __ATOMIC_RELAXED, __HIP_MEMORY_SCOPE_AGENT);
  __hip_atomic_store(q + 1, c1.u, __ATOMIC_RELAXED, __HIP_MEMORY_SCOPE_AGENT);
}

// ---- fence-free DOMAIN barrier over blocks [first, first+n). No cache maintenance.
__device__ __forceinline__ void gbarD(unsigned* bar, int ep, int first, int n) {
  asm volatile("s_waitcnt vmcnt(0) lgkmcnt(0)" ::: "memory");
  __syncthreads();
  const int tid = threadIdx.x;
  const int rel = (int)blockIdx.x - first;
  if (tid == 0)
    __hip_atomic_store(bar + (size_t)rel * 16, (unsigned)ep,
                       __ATOMIC_RELAXED, __HIP_MEMORY_SCOPE_AGENT);
  if (rel == 0) {
    if (tid < n)
      while (__hip_atomic_load(bar + (size_t)tid * 16,
                               __ATOMIC_RELAXED, __HIP_MEMORY_SCOPE_AGENT) < (unsigned)ep)
        __builtin_amdgcn_s_sleep(1);
    __syncthreads();
    if (tid == 0)
      __hip_atomic_store(bar + (size_t)n * 16, (unsigned)ep,
                         __ATOMIC_RELAXED, __HIP_MEMORY_SCOPE_AGENT);
  } else if (tid == 0) {
    while (__hip_atomic_load(bar + (size_t)n * 16,
                             __ATOMIC_RELAXED, __HIP_MEMORY_SCOPE_AGENT) < (unsigned)ep)
      __builtin_amdgcn_s_sleep(1);
  }
  __syncthreads();
}

// 4-way reduce over kq (lane = kq*16 + r)
__device__ __forceinline__ float red4(float v) {
  v += __shfl_down(v, 16, 64);
  v += __shfl_down(v, 32, 64);
  return v;
}

// ---------------- diag ----------------
__global__ void k_diag(float* out, float v) {
  int i = blockIdx.x * 64 + threadIdx.x;
  if (i < BB * 3) out[i] = v;
}

// ---------------- K0: weight transpose/stack + state/slot zero ----------------
__global__ __launch_bounds__(256) void k_prep(float* ws,
    const float* Wih_p, const float* bih_p, const float* bhh_p,
    const float* Wih_h, const float* bih_h, const float* bhh_h,
    const float* Whh_p, const float* Whh_h,
    const float* Whh_m, const float* Wih_m, const float* bih_m, const float* bhh_m,
    const float* W_m, const float* W_t, const float* w_e) {
  size_t gid = (size_t)blockIdx.x * 256 + threadIdx.x;
  if (gid < SZ_WIHT) {
    int k = (int)(gid >> 11), r = (int)(gid & 2047);
    float v = (k < 300) ? Wih_p[(size_t)r * 300 + k]
            : (k == 303) ? (bih_p[r] + bhh_p[r]) : 0.f;
    ws[OFF_WIHT_P + gid] = v;
    return;
  }
  gid -= SZ_WIHT;
  if (gid < SZ_WIHT) {
    int k = (int)(gid >> 11), r = (int)(gid & 2047);
    float v = (k < 300) ? Wih_h[(size_t)r * 300 + k]
            : (k == 303) ? (bih_h[r] + bhh_h[r]) : 0.f;
    ws[OFF_WIHT_H + gid] = v;
    return;
  }
  gid -= SZ_WIHT;
  const size_t NT = (size_t)512 * 2048;
  if (gid < NT) {  // WL_P [c=j*4+g][k]
    int c = (int)(gid >> 9), kk = (int)(gid & 511);
    int j = c >> 2, g = c & 3;
    ws[OFF_WHHT_P + gid] = Whh_p[(size_t)(g * 512 + j) * 512 + kk];
    return;
  }
  gid -= NT;
  if (gid < NT) {  // WL_H
    int c = (int)(gid >> 9), kk = (int)(gid & 511);
    int j = c >> 2, g = c & 3;
    ws[OFF_WHHT_H + gid] = Whh_h[(size_t)(g * 512 + j) * 512 + kk];
    return;
  }
  gid -= NT;
  if (gid < (size_t)2560 * 1024) {  // WB1T [c][k]
    int c = (int)(gid >> 10), k = (int)(gid & 1023);
    float v;
    if (c < 512) {
      v = (k < 512) ? W_m[(size_t)c * 512 + k] : W_t[(size_t)c * 512 + (k - 512)];
    } else {
      int p = c - 512;
      int j = p >> 2, g = p & 3;
      int r = g * 512 + j;
      v = (k < 512) ? Whh_m[(size_t)r * 512 + k] : Wih_m[(size_t)r * 1024 + k];
    }
    ws[OFF_WB1T + gid] = v;
    return;
  }
  gid -= (size_t)2560 * 1024;
  if (gid < (size_t)2048 * 512) {  // WIAT [c][k]
    int c = (int)(gid >> 9), k = (int)(gid & 511);
    int j = c >> 2, g = c & 3;
    ws[OFF_WIA + gid] = Wih_m[((size_t)g * 512 + j) * 1024 + k];
    return;
  }
  gid -= (size_t)2048 * 512;
  if (gid < 512) { ws[OFF_WEF + gid] = w_e[gid]; return; }
  gid -= 512;
  if (gid < 2048) { ws[OFF_BM + gid] = bih_m[gid] + bhh_m[gid]; return; }
  gid -= 2048;
  if (gid < (size_t)393216) { ws[OFF_HC_P + gid] = 0.f; return; }  // HC_P,HC_H,C_P,C_H
  gid -= 393216;
  if (gid < (size_t)131072) { ws[OFF_HM + gid] = 0.f; return; }    // HM, CM
  gid -= 131072;
  if (gid < 13824) { ws[OFF_BARP + gid] = 0.f; return; }           // ALL barrier slots
}

// ---------------- generic 64x64-tile fp32 GEMM (Ws = HS @ W_s^T) ----------------
__global__ __launch_bounds__(256) void k_gemm(const float* __restrict__ A,
                                              const float* __restrict__ Bw, int ldb, int Kdim,
                                              int N, float* __restrict__ C, int ntilesN) {
  __shared__ float As[16][68];
  __shared__ float Bs[16][68];
  const int tid = threadIdx.x;
  const int bid = blockIdx.x;
  const int tm = bid / ntilesN, tn = bid % ntilesN;
  const int m0 = tm * 64, n0 = tn * 64;
  const int tx = tid & 15, ty = tid >> 4;
  const int srow = tid >> 2, skc = (tid & 3) * 4;
  float acc[4][4] = {};
  const float* arowf = A + (size_t)(m0 + srow) * Kdim;
  const float* brow = Bw + (size_t)(n0 + srow) * ldb;
  for (int k0 = 0; k0 < Kdim; k0 += 16) {
    float4 v = *(const float4*)(arowf + k0 + skc);
    As[skc + 0][srow] = v.x; As[skc + 1][srow] = v.y;
    As[skc + 2][srow] = v.z; As[skc + 3][srow] = v.w;
#pragma unroll
    for (int i = 0; i < 4; i++) Bs[skc + i][srow] = brow[k0 + skc + i];
    __syncthreads();
#pragma unroll
    for (int kk = 0; kk < 16; kk++) {
      float4 a4 = *(float4*)&As[kk][ty * 4];
      float4 b4 = *(float4*)&Bs[kk][tx * 4];
      acc[0][0] += a4.x * b4.x; acc[0][1] += a4.x * b4.y; acc[0][2] += a4.x * b4.z; acc[0][3] += a4.x * b4.w;
      acc[1][0] += a4.y * b4.x; acc[1][1] += a4.y * b4.y; acc[1][2] += a4.y * b4.z; acc[1][3] += a4.y * b4.w;
      acc[2][0] += a4.z * b4.x; acc[2][1] += a4.z * b4.y; acc[2][2] += a4.z * b4.z; acc[2][3] += a4.z * b4.w;
      acc[3][0] += a4.w * b4.x; acc[3][1] += a4.w * b4.y; acc[3][2] += a4.w * b4.z; acc[3][3] += a4.w * b4.w;
    }
    __syncthreads();
  }
  const int m = m0 + ty * 4, n = n0 + tx * 4;
#pragma unroll
  for (int i = 0; i < 4; i++) {
    float4 o = {acc[i][0], acc[i][1], acc[i][2], acc[i][3]};
    *(float4*)&C[(size_t)(m + i) * N + n] = o;
  }
}

// ---------------- persistent LSTM: 256 blocks x 512 thr; 16 independent 16-block domains ----
// Domain = (seq, b-group of 16 rows). Block (gb, gj): 16 b x 128 c (c=j*4+g).
// Wave owns 16 c (wave-uniform W loads from L2); lanes = 16 b x 4 k-stripes; shfl-reduce.
// h carry: atomic (32 KB/block/step); W: cached stream; xg: domain-local window GEMM.
__global__ __launch_bounds__(512) void k_lstm_mega(float* __restrict__ ws,
    const int* __restrict__ premise, const int* __restrict__ hyp,
    const int* __restrict__ plen, const int* __restrict__ hlen,
    const float* __restrict__ emb) {
  __shared__ float4 smem4[4096];           // 64 KB
  float4* Alds4 = smem4;                   // step: h tile [16 b][128 k4] swizzled (32 KB)
  float* xAs = (float*)(smem4 + 2048);     // window: [16][68]
  float* xBs = xAs + 16 * 68;
  int* xTok = (int*)(xBs + 16 * 68);

  const int tid = threadIdx.x;
  const int bid = blockIdx.x;
  const int seq = bid >> 7;
  const int u = bid & 127;
  const int gb = u >> 4, gj = u & 15;
  const int T = seq ? THh : TPp;
  const int* toks = seq ? hyp : premise;
  const int* lens = seq ? hlen : plen;
  const float* WL = ws + (seq ? OFF_WHHT_H : OFF_WHHT_P);  // [2048 c][512 k]
  const float* WX = ws + (seq ? OFF_WIHT_H : OFF_WIHT_P);  // [304][2048]
  float* hc = ws + (seq ? OFF_HC_H : OFF_HC_P);
  float* hsout = ws + (seq ? OFF_HT : OFF_HS);
  float* xgd = ws + OFF_WSM + (size_t)(seq * 8 + gb) * (16 * 16 * 2048);
  unsigned* bar = (unsigned*)(ws + (seq ? OFF_BARH : OFF_BARP)) + gb * 272;
  const int dfirst = seq * 128 + gb * 16;

  const int w = tid >> 6, lane = tid & 63;
  const int b_loc = lane & 15, kq = lane >> 4;
  const int b_glob = gb * 16 + b_loc;
  const int c0 = gj * 128 + w * 16;
  const int j0 = c0 >> 2;
  const int len = lens[b_glob];
  float c_r[4] = {0.f, 0.f, 0.f, 0.f}, h_r[4] = {0.f, 0.f, 0.f, 0.f};
  int ep = 1;

  for (int t = 0; t < T; t++) {
    if ((t & 15) == 0) {
      // ---- window: domain-local xg GEMM (rows = 16 t x 16 b, cols = 2048) ----
      for (int ti = gj; ti < 128; ti += 16) {
        const int tm = ti >> 5, tn = ti & 31;
        const int m0 = tm * 64, n0 = tn * 64;
        if (tid < 64) {
          int rr = m0 + tid;
          int tl = rr >> 4, bl = rr & 15;
          xTok[tid] = toks[(size_t)(gb * 16 + bl) * T + t + tl];
        }
        __syncthreads();
        const int sr = tid & 63, sk2 = (tid >> 6) * 2;
        const int tx = tid & 15, ty = tid >> 4;
        float acc2[2][4] = {};
        for (int k0 = 0; k0 < 304; k0 += 16) {
          int tok = xTok[sr];
#pragma unroll
          for (int i = 0; i < 2; i++) {
            int kx = k0 + sk2 + i;
            float v = 0.f;
            if (kx < 300) v = emb[(size_t)tok * 300 + kx];
            else if (kx == 303) v = 1.0f;
            xAs[(sk2 + i) * 68 + sr] = v;
          }
#pragma unroll
          for (int s = 0; s < 2; s++) {
            int i2 = tid + s * 512;
            int kb = i2 >> 6, nb = i2 & 63;
            xBs[kb * 68 + nb] = WX[(size_t)(k0 + kb) * 2048 + n0 + nb];
          }
          __syncthreads();
#pragma unroll
          for (int kk = 0; kk < 16; kk++) {
            float a0 = xAs[kk * 68 + ty * 2];
            float a1 = xAs[kk * 68 + ty * 2 + 1];
            float4 b4 = *(float4*)&xBs[kk * 68 + tx * 4];
            acc2[0][0] += a0 * b4.x; acc2[0][1] += a0 * b4.y; acc2[0][2] += a0 * b4.z; acc2[0][3] += a0 * b4.w;
            acc2[1][0] += a1 * b4.x; acc2[1][1] += a1 * b4.y; acc2[1][2] += a1 * b4.z; acc2[1][3] += a1 * b4.w;
          }
          __syncthreads();
        }
#pragma unroll
        for (int i = 0; i < 2; i++) {
          int rr = m0 + ty * 2 + i;
          int tl = rr >> 4, bl = rr & 15;
          float* dst = xgd + ((size_t)tl * 16 + bl) * 2048;
#pragma unroll
          for (int jj = 0; jj < 4; jj++) {
            int cI = n0 + tx * 4 + jj;
            int g = cI >> 9, j = cI & 511;
            astore4(dst + j * 4 + g, acc2[i][jj]);
          }
        }
      }
      gbarD(bar, ep, dfirst, 16); ep++;
    }
    // ---- step t ----
    {
      const float* hin = hc + (size_t)(t & 1) * (BB * HH);
      float* hout = hc + (size_t)((t + 1) & 1) * (BB * HH);
#pragma unroll
      for (int i = 0; i < 4; i++) {
        int f = tid + 512 * i;
        int bl = f >> 7, k4 = f & 127;
        Alds4[bl * 128 + (k4 ^ (bl & 7))] = aload16(hin + (size_t)(gb * 16 + bl) * 512 + k4 * 4);
      }
      __syncthreads();
      float acc[16];
#pragma unroll
      for (int c = 0; c < 16; c++) acc[c] = 0.f;
      for (int it = 0; it < 32; it++) {
        int kk = it * 16 + kq * 4;
        float4 a4 = Alds4[b_loc * 128 + ((it * 4 + kq) ^ (b_loc & 7))];
#pragma unroll
        for (int cq = 0; cq < 16; cq++) {
          float4 w4 = *(const float4*)&WL[(size_t)(c0 + cq) * 512 + kk];
          acc[cq] += a4.x * w4.x + a4.y * w4.y + a4.z * w4.z + a4.w * w4.w;
        }
      }
#pragma unroll
      for (int cq = 0; cq < 16; cq++) acc[cq] = red4(acc[cq]);
      if (kq == 0) {
        const float* xb = xgd + ((size_t)(t & 15) * 16 + b_loc) * 2048 + c0;
        float4 hv;
        float* hvp = (float*)&hv;
        bool inr = t < len;
#pragma unroll
        for (int jl = 0; jl < 4; jl++) {
          float4 xa = aload16(xb + jl * 4);
          float iv = sigmf(acc[jl * 4 + 0] + xa.x);
          float fv = sigmf(acc[jl * 4 + 1] + xa.y);
          float gv = tanh_f(acc[jl * 4 + 2] + xa.z);
          float ov = sigmf(acc[jl * 4 + 3] + xa.w);
          float cn = fv * c_r[jl] + iv * gv;
          float hn = ov * tanh_f(cn);
          if (inr) { c_r[jl] = cn; h_r[jl] = hn; }
          hvp[jl] = inr ? hn : 0.f;
        }
        *(float4*)(hsout + ((size_t)b_glob * T + t) * 512 + j0) = hv;
        float4 ho = {h_r[0], h_r[1], h_r[2], h_r[3]};
        astore16(hout + (size_t)b_glob * 512 + j0, ho);
      }
      gbarD(bar, ep, dfirst, 16); ep++;
    }
  }
}

// ---------------- persistent match: 256 blocks x 512 thr; 8 independent 32-block stripes ----
// Stripe gr owns 16 batch rows. Block (gr, gc): P1 = 16 r x 80 c; P2 = row gr*16+gc (gc<16);
// P3 = 16 r x 16 j. Wave-uniform weight loads (B1/W3 from L2); A staged once/phase to LDS.
__global__ __launch_bounds__(512) void k_match_mega(float* __restrict__ ws,
                                                    const int* __restrict__ hlen) {
  __shared__ float4 smem4[4096];  // 64 KB
  float4* A1 = smem4;             // P1: [16 r][256 k4] swz (64 KB)
  float4* A3 = smem4;             // P3: [16 r][128 k4] swz (32 KB)
  float* SC = (float*)smem4;      // P2 scratch

  const int tid = threadIdx.x;
  const int bid = blockIdx.x;
  const int gr = bid >> 5, gc = bid & 31;
  const int dfirst = gr * 32;
  unsigned* bar = (unsigned*)(ws + OFF_BARM) + gr * 528;

  float* hm = ws + OFF_HM;
  const float* ht = ws + OFF_HT;
  float* q = ws + OFF_Q;
  float* gh = ws + OFF_GH;
  float* abuf = ws + OFF_A;
  float* last = ws + OFF_LAST;
  const float* B1 = ws + OFF_WB1T;
  const float* W3 = ws + OFF_WIA;

  const int w = tid >> 6, lane = tid & 63;
  const int rl = lane & 15, kq = lane >> 4;
  const int r_g = gr * 16 + rl;
  const int c0p = gc * 80 + w * 10;   // P1 col base (packed 0..2559)
  const int c0q = gc * 64 + w * 8;    // P3 col base (packed 0..2047)
  const int jq = c0q >> 2;            // P3 first j (2 j per wave)
  float c_reg[2] = {0.f, 0.f};
  const int hl = hlen[r_g];
  float bmp[8];
#pragma unroll
  for (int jl = 0; jl < 2; jl++)
#pragma unroll
    for (int g = 0; g < 4; g++) bmp[jl * 4 + g] = ws[OFF_BM + g * 512 + jq + jl];
  int ep = 1;

  for (int k = 0; k < THh; k++) {
    // ---------- P1: q/gh rows of gr = [hm | ht_k] @ B1 cols [c0p..c0p+9] ----------
    {
#pragma unroll
      for (int i = 0; i < 8; i++) {
        int f = tid + 512 * i;
        int rr = f >> 8, k4 = f & 255;
        float4 v;
        if (k4 < 128) v = aload16(&hm[(size_t)(gr * 16 + rr) * 512 + k4 * 4]);
        else v = *(const float4*)&ht[((size_t)(gr * 16 + rr) * THh + k) * 512 + (k4 - 128) * 4];
        A1[rr * 256 + (k4 ^ (rr & 7))] = v;
      }
      __syncthreads();
      float acc[10];
#pragma unroll
      for (int cc = 0; cc < 10; cc++) acc[cc] = 0.f;
      for (int it = 0; it < 64; it++) {
        int kk = it * 16 + kq * 4;
        float4 a4 = A1[rl * 256 + ((it * 4 + kq) ^ (rl & 7))];
#pragma unroll
        for (int cc = 0; cc < 10; cc++) {
          float4 b4 = *(const float4*)&B1[(size_t)(c0p + cc) * 1024 + kk];
          acc[cc] += a4.x * b4.x + a4.y * b4.y + a4.z * b4.z + a4.w * b4.w;
        }
      }
#pragma unroll
      for (int cc = 0; cc < 10; cc++) acc[cc] = red4(acc[cc]);
      if (kq == 0) {
#pragma unroll
        for (int cc = 0; cc < 10; cc++) {
          int c = c0p + cc;
          if (c < 512) astore4(&q[(size_t)r_g * 512 + c], acc[cc]);
          else astore4(&gh[(size_t)r_g * 2048 + (c - 512)], acc[cc]);
        }
      }
    }
    gbarD(bar, ep, dfirst, 32); ep++;
    // ---------- P2: attention for row b = gr*16+gc (blocks gc<16) ----------
    if (gc < 16) {
      const int b = gr * 16 + gc;
      float* q_lds = SC; float* we_lds = SC + 512; float* e_part = SC + 1024;
      float* e_lds = SC + 1536; float* alpha_lds = SC + 1664; float* red_s = SC + 1792;
      const float* Wsb = ws + OFF_WSM;
      const float* hs = ws + OFF_HS;
      q_lds[tid] = aload4(&q[(size_t)b * 512 + tid]);
      we_lds[tid] = ws[OFF_WEF + tid];
      __syncthreads();
      {
        int t2 = tid >> 2;
        int gbase = (tid & 3) * 128;
        const float* wsrow = Wsb + ((size_t)b * TPp + t2) * 512 + gbase;
        float s = 0.f;
        for (int ii = 0; ii < 128; ii += 4) {
          float4 wv = *(const float4*)(wsrow + ii);
          float4 qv = *(float4*)&q_lds[gbase + ii];
          float4 ev = *(float4*)&we_lds[gbase + ii];
          s += tanh_f(wv.x + qv.x) * ev.x + tanh_f(wv.y + qv.y) * ev.y +
               tanh_f(wv.z + qv.z) * ev.z + tanh_f(wv.w + qv.w) * ev.w;
        }
        e_part[tid] = s;
      }
      __syncthreads();
      if (tid < 128)
        e_lds[tid] = e_part[tid * 4] + e_part[tid * 4 + 1] + e_part[tid * 4 + 2] + e_part[tid * 4 + 3];
      __syncthreads();
      if (tid < 64) {
        float m = fmaxf(e_lds[tid], e_lds[tid + 64]);
        for (int off = 32; off > 0; off >>= 1) m = fmaxf(m, __shfl_down(m, off));
        if (tid == 0) red_s[0] = m;
      }
      __syncthreads();
      if (tid < 128) alpha_lds[tid] = __expf(e_lds[tid] - red_s[0]);
      __syncthreads();
      if (tid < 64) {
        float s = alpha_lds[tid] + alpha_lds[tid + 64];
        for (int off = 32; off > 0; off >>= 1) s += __shfl_down(s, off);
        if (tid == 0) red_s[1] = 1.f / s;
      }
      __syncthreads();
      {
        float inv = red_s[1];
        float a0 = 0.f;
        const float* hsb = hs + (size_t)b * TPp * 512 + tid;
        for (int t2 = 0; t2 < TPp; t2++) a0 += alpha_lds[t2] * hsb[(size_t)t2 * 512];
        astore4(&abuf[(size_t)b * 512 + tid], a0 * inv);
      }
    }
    gbarD(bar, ep, dfirst, 32); ep++;
    // ---------- P3: cell update for rows of gr, j in [gc*16, gc*16+16) ----------
    {
#pragma unroll
      for (int i = 0; i < 4; i++) {
        int f = tid + 512 * i;
        int rr = f >> 7, k4 = f & 127;
        A3[rr * 128 + (k4 ^ (rr & 7))] = aload16(&abuf[(size_t)(gr * 16 + rr) * 512 + k4 * 4]);
      }
      __syncthreads();
      float acc[8];
#pragma unroll
      for (int cc = 0; cc < 8; cc++) acc[cc] = 0.f;
      for (int it = 0; it < 32; it++) {
        int kk = it * 16 + kq * 4;
        float4 a4 = A3[rl * 128 + ((it * 4 + kq) ^ (rl & 7))];
#pragma unroll
        for (int cc = 0; cc < 8; cc++) {
          float4 w4 = *(const float4*)&W3[(size_t)(c0q + cc) * 512 + kk];
          acc[cc] += a4.x * w4.x + a4.y * w4.y + a4.z * w4.z + a4.w * w4.w;
        }
      }
#pragma unroll
      for (int cc = 0; cc < 8; cc++) acc[cc] = red4(acc[cc]);
      if (kq == 0) {
#pragma unroll
        for (int jl = 0; jl < 2; jl++) {
          float4 gh4 = aload16(&gh[(size_t)r_g * 2048 + c0q + jl * 4]);
          float iv = sigmf(acc[jl * 4 + 0] + gh4.x + bmp[jl * 4 + 0]);
          float fv = sigmf(acc[jl * 4 + 1] + gh4.y + bmp[jl * 4 + 1]);
          float gv = tanh_f(acc[jl * 4 + 2] + gh4.z + bmp[jl * 4 + 2]);
          float ov = sigmf(acc[jl * 4 + 3] + gh4.w + bmp[jl * 4 + 3]);
          float cn = fv * c_reg[jl] + iv * gv;
          float hn = ov * tanh_f(cn);
          c_reg[jl] = cn;
          astore4(&hm[(size_t)r_g * 512 + jq + jl], hn);
          if (k == hl - 1) last[(size_t)r_g * 512 + jq + jl] = hn;
        }
      }
    }
    gbarD(bar, ep, dfirst, 32); ep++;
  }
}

// ---------------- FC epilogue ----------------
__global__ __launch_bounds__(256) void k_fc(const float* __restrict__ ws, const float* __restrict__ Wfc,
                                            const float* __restrict__ bfc, float* __restrict__ out) {
  int idx = blockIdx.x * 256 + threadIdx.x;
  if (idx >= BB * 3) return;
  int b = idx / 3, o = idx - b * 3;
  const float* lrow = ws + OFF_LAST + (size_t)b * 512;
  const float* wrow = Wfc + (size_t)o * 512;
  float acc = bfc[o];
  for (int h = 0; h < 512; h++) acc += lrow[h] * wrow[h];
  out[idx] = acc;
}

extern "C" void kernel_launch(void* const* d_in, const int* in_sizes, int n_in, void* d_out,
                              int out_size, void* d_ws, size_t ws_size, hipStream_t stream) {
  const int* premise = (const int*)d_in[0];
  const int* plen = (const int*)d_in[1];
  const int* hyp = (const int*)d_in[2];
  const int* hlen = (const int*)d_in[3];
  const float* emb = (const float*)d_in[4];
  const float* Wih_p = (const float*)d_in[5];
  const float* Whh_p = (const float*)d_in[6];
  const float* bih_p = (const float*)d_in[7];
  const float* bhh_p = (const float*)d_in[8];
  const float* Wih_h = (const float*)d_in[9];
  const float* Whh_h = (const float*)d_in[10];
  const float* bih_h = (const float*)d_in[11];
  const float* bhh_h = (const float*)d_in[12];
  const float* Wih_m = (const float*)d_in[13];
  const float* Whh_m = (const float*)d_in[14];
  const float* bih_m = (const float*)d_in[15];
  const float* bhh_m = (const float*)d_in[16];
  const float* w_e = (const float*)d_in[17];
  const float* W_s = (const float*)d_in[18];
  const float* W_t = (const float*)d_in[19];
  const float* W_m = (const float*)d_in[20];
  const float* W_fc = (const float*)d_in[21];
  const float* b_fc = (const float*)d_in[22];
  float* ws = (float*)d_ws;
  float* out = (float*)d_out;

  if (ws_size < WS_FLOATS * sizeof(float)) {
    float mb = (float)((double)ws_size / (1024.0 * 1024.0));
    k_diag<<<dim3(6), dim3(64), 0, stream>>>(out, mb);
    return;
  }

  // K0: weight prep + state/slot zero
  {
    size_t total = 2 * SZ_WIHT + 2 * (size_t)512 * 2048 + (size_t)2560 * 1024 +
                   (size_t)2048 * 512 + 512 + 2048 + 393216 + 131072 + 13824;
    int nb = (int)((total + 255) / 256);
    k_prep<<<dim3(nb), dim3(256), 0, stream>>>(ws, Wih_p, bih_p, bhh_p, Wih_h, bih_h, bhh_h,
                                               Whh_p, Whh_h, Whh_m, Wih_m, bih_m, bhh_m,
                                               W_m, W_t, w_e);
  }
  // persistent LSTM (16 independent 16-block domains)
  {
    void* args[] = {(void*)&ws, (void*)&premise, (void*)&hyp, (void*)&plen, (void*)&hlen, (void*)&emb};
    hipError_t e = hipLaunchCooperativeKernel((const void*)k_lstm_mega, dim3(256), dim3(512),
                                              args, 0, stream);
    if (e != hipSuccess)
      k_lstm_mega<<<dim3(256), dim3(512), 0, stream>>>(ws, premise, hyp, plen, hlen, emb);
  }
  // Ws = HS @ W_s^T (WSM region free again)
  k_gemm<<<dim3(256 * 8), dim3(256), 0, stream>>>(ws + OFF_HS, W_s, 512, 512, 512,
                                                  ws + OFF_WSM, 8);
  // persistent match loop (8 independent 32-block stripes, 3 domain barriers/step)
  {
    void* args[] = {(void*)&ws, (void*)&hlen};
    hipError_t e = hipLaunchCooperativeKernel((const void*)k_match_mega, dim3(256), dim3(512),
                                              args, 0, stream);
    if (e != hipSuccess)
      k_match_mega<<<dim3(256), dim3(512), 0, stream>>>(ws, hlen);
  }
  // FC epilogue
  k_fc<<<dim3(2), dim3(256), 0, stream>>>(ws, W_fc, b_fc, out);
}

// Round 8
// 12428.017 us; speedup vs baseline: 1.0511x; 1.0511x over previous
//
#include <hip/hip_runtime.h>

// Problem constants
constexpr int BB = 128;   // batch
constexpr int TPp = 128;  // premise len
constexpr int THh = 64;   // hypothesis len
constexpr int HH = 512;   // hidden

// ---------------- workspace layout (fp32 words) ----------------
constexpr size_t OFF_HS     = 0;                               // premise h history [b][t][512]
constexpr size_t SZ_HS      = (size_t)16384 * 512;
constexpr size_t OFF_HT     = OFF_HS + SZ_HS;                  // hyp h history [b][t][512]
constexpr size_t SZ_HT      = (size_t)8192 * 512;
constexpr size_t OFF_WSM    = OFF_HT + SZ_HT;                  // Ws (match) / LSTM block-private xg [bid][16t][16b][128c]
constexpr size_t SZ_WSM     = (size_t)16384 * 512;
constexpr size_t OFF_WIHT_P = OFF_WSM + SZ_WSM;                // [304 k][2048 PACKED c=j*4+g]; k 300-302 zero, 303=bih+bhh
constexpr size_t SZ_WIHT    = (size_t)304 * 2048;
constexpr size_t OFF_WIHT_H = OFF_WIHT_P + SZ_WIHT;
constexpr size_t OFF_WHHT_P = OFF_WIHT_H + SZ_WIHT;            // WL_P [2048 c][512 k], c=j*4+g
constexpr size_t OFF_WHHT_H = OFF_WHHT_P + (size_t)512 * 2048; // WL_H
constexpr size_t OFF_WB1T   = OFF_WHHT_H + (size_t)512 * 2048; // [2560 c][1024 k]
constexpr size_t OFF_WIA    = OFF_WB1T + (size_t)2560 * 1024;  // WIAT [2048 c][512 k], c=j*4+g
constexpr size_t OFF_WEF    = OFF_WIA + (size_t)2048 * 512;    // w_e [512]
constexpr size_t OFF_BM     = OFF_WEF + 512;                   // bih_m+bhh_m [2048]
constexpr size_t OFF_HC_P   = OFF_BM + 2048;                   // 2 x [128][512] h carry dbuf (premise)
constexpr size_t OFF_HC_H   = OFF_HC_P + 2 * (size_t)BB * HH;  // 2 x [128][512] (hyp)
constexpr size_t OFF_C_P    = OFF_HC_H + 2 * (size_t)BB * HH;  // vestigial (zeroed)
constexpr size_t OFF_C_H    = OFF_C_P + (size_t)BB * HH;
constexpr size_t OFF_Q      = OFF_C_H + (size_t)BB * HH;       // q [128 r][512 c]
constexpr size_t OFF_GH     = OFF_Q + (size_t)BB * HH;         // gh [128 r][2048 c], c=j*4+g
constexpr size_t OFF_A      = OFF_GH + (size_t)BB * 2048;      // abuf [128 b][512 j]
constexpr size_t OFF_HM     = OFF_A + (size_t)BB * HH;         // hm [128 r][512 j]
constexpr size_t OFF_CM     = OFF_HM + (size_t)BB * HH;        // vestigial (zeroed)
constexpr size_t OFF_LAST   = OFF_CM + (size_t)BB * HH;        // [128 r][512 j]
constexpr size_t OFF_BARP   = OFF_LAST + (size_t)BB * HH;      // premise domain barriers: 8 doms x 272
constexpr size_t OFF_BARH   = OFF_BARP + 2560;                 // hyp domain barriers
constexpr size_t OFF_BARF   = OFF_BARH + 2560;                 // unused (zeroed)
constexpr size_t OFF_BARM   = OFF_BARF + 4352;                 // match domain barriers: 8 doms x 528
constexpr size_t WS_FLOATS  = OFF_BARM + 4352;

__device__ __forceinline__ float sigmf(float x) { return 1.0f / (1.0f + __expf(-x)); }
__device__ __forceinline__ float tanh_f(float x) {
  float e = __expf(-2.0f * fabsf(x));
  float r = (1.0f - e) / (1.0f + e);
  return copysignf(r, x);
}

// ---- device-coherent (sc0 sc1) access for cross-block mutable data ----
__device__ __forceinline__ float aload4(const float* p) {
  unsigned u = __hip_atomic_load((const unsigned*)p, __ATOMIC_RELAXED, __HIP_MEMORY_SCOPE_AGENT);
  return __uint_as_float(u);
}
__device__ __forceinline__ void astore4(float* p, float v) {
  __hip_atomic_store((unsigned*)p, __float_as_uint(v), __ATOMIC_RELAXED, __HIP_MEMORY_SCOPE_AGENT);
}
__device__ __forceinline__ float4 aload16(const float* p) {
  const unsigned long long* q = (const unsigned long long*)p;
  unsigned long long u0 = __hip_atomic_load(q, __ATOMIC_RELAXED, __HIP_MEMORY_SCOPE_AGENT);
  unsigned long long u1 = __hip_atomic_load(q + 1, __ATOMIC_RELAXED, __HIP_MEMORY_SCOPE_AGENT);
  union { unsigned long long u; float2 f; } c0, c1;
  c0.u = u0; c1.u = u1;
  float4 f; f.x = c0.f.x; f.y = c0.f.y; f.z = c1.f.x; f.w = c1.f.y;
  return f;
}
__device__ __forceinline__ void astore16(float* p, float4 v) {
  union { unsigned long long u; float2 f; } c0, c1;
  c0.f.x = v.x; c0.f.y = v.y; c1.f.x = v.z; c1.f.y = v.w;
  unsigned long long* q = (unsigned long long*)p;
  __hip_atomic_store(q, c0.u, __ATOMIC_RELAXED, __HIP_MEMORY_SCOPE_AGENT);
  __hip_atomic_store(q + 1, c1.u, __ATOMIC_RELAXED, __HIP_MEMORY_SCOPE_AGENT);
}

// ---- fence-free DOMAIN barrier over blocks [first, first+n). No cache maintenance.
__device__ __forceinline__ void gbarD(unsigned* bar, int ep, int first, int n) {
  asm volatile("s_waitcnt vmcnt(0) lgkmcnt(0)" ::: "memory");
  __syncthreads();
  const int tid = threadIdx.x;
  const int rel = (int)blockIdx.x - first;
  if (tid == 0)
    __hip_atomic_store(bar + (size_t)rel * 16, (unsigned)ep,
                       __ATOMIC_RELAXED, __HIP_MEMORY_SCOPE_AGENT);
  if (rel == 0) {
    if (tid < n)
      while (__hip_atomic_load(bar + (size_t)tid * 16,
                               __ATOMIC_RELAXED, __HIP_MEMORY_SCOPE_AGENT) < (unsigned)ep)
        __builtin_amdgcn_s_sleep(1);
    __syncthreads();
    if (tid == 0)
      __hip_atomic_store(bar + (size_t)n * 16, (unsigned)ep,
                         __ATOMIC_RELAXED, __HIP_MEMORY_SCOPE_AGENT);
  } else if (tid == 0) {
    while (__hip_atomic_load(bar + (size_t)n * 16,
                             __ATOMIC_RELAXED, __HIP_MEMORY_SCOPE_AGENT) < (unsigned)ep)
      __builtin_amdgcn_s_sleep(1);
  }
  __syncthreads();
}

// 4-way reduce over kq (lane = kq*16 + r)
__device__ __forceinline__ float red4(float v) {
  v += __shfl_down(v, 16, 64);
  v += __shfl_down(v, 32, 64);
  return v;
}

// ---------------- diag ----------------
__global__ void k_diag(float* out, float v) {
  int i = blockIdx.x * 64 + threadIdx.x;
  if (i < BB * 3) out[i] = v;
}

// ---------------- K0: weight transpose/stack + state/slot zero ----------------
__global__ __launch_bounds__(256) void k_prep(float* ws,
    const float* Wih_p, const float* bih_p, const float* bhh_p,
    const float* Wih_h, const float* bih_h, const float* bhh_h,
    const float* Whh_p, const float* Whh_h,
    const float* Whh_m, const float* Wih_m, const float* bih_m, const float* bhh_m,
    const float* W_m, const float* W_t, const float* w_e) {
  size_t gid = (size_t)blockIdx.x * 256 + threadIdx.x;
  if (gid < SZ_WIHT) {  // WIHT_P PACKED: [k][c=j*4+g]
    int k = (int)(gid >> 11), c = (int)(gid & 2047);
    int j = c >> 2, g = c & 3;
    int row = g * 512 + j;
    float v = (k < 300) ? Wih_p[(size_t)row * 300 + k]
            : (k == 303) ? (bih_p[row] + bhh_p[row]) : 0.f;
    ws[OFF_WIHT_P + gid] = v;
    return;
  }
  gid -= SZ_WIHT;
  if (gid < SZ_WIHT) {  // WIHT_H PACKED
    int k = (int)(gid >> 11), c = (int)(gid & 2047);
    int j = c >> 2, g = c & 3;
    int row = g * 512 + j;
    float v = (k < 300) ? Wih_h[(size_t)row * 300 + k]
            : (k == 303) ? (bih_h[row] + bhh_h[row]) : 0.f;
    ws[OFF_WIHT_H + gid] = v;
    return;
  }
  gid -= SZ_WIHT;
  const size_t NT = (size_t)512 * 2048;
  if (gid < NT) {  // WL_P [c=j*4+g][k]
    int c = (int)(gid >> 9), kk = (int)(gid & 511);
    int j = c >> 2, g = c & 3;
    ws[OFF_WHHT_P + gid] = Whh_p[(size_t)(g * 512 + j) * 512 + kk];
    return;
  }
  gid -= NT;
  if (gid < NT) {  // WL_H
    int c = (int)(gid >> 9), kk = (int)(gid & 511);
    int j = c >> 2, g = c & 3;
    ws[OFF_WHHT_H + gid] = Whh_h[(size_t)(g * 512 + j) * 512 + kk];
    return;
  }
  gid -= NT;
  if (gid < (size_t)2560 * 1024) {  // WB1T [c][k]
    int c = (int)(gid >> 10), k = (int)(gid & 1023);
    float v;
    if (c < 512) {
      v = (k < 512) ? W_m[(size_t)c * 512 + k] : W_t[(size_t)c * 512 + (k - 512)];
    } else {
      int p = c - 512;
      int j = p >> 2, g = p & 3;
      int r = g * 512 + j;
      v = (k < 512) ? Whh_m[(size_t)r * 512 + k] : Wih_m[(size_t)r * 1024 + k];
    }
    ws[OFF_WB1T + gid] = v;
    return;
  }
  gid -= (size_t)2560 * 1024;
  if (gid < (size_t)2048 * 512) {  // WIAT [c][k]
    int c = (int)(gid >> 9), k = (int)(gid & 511);
    int j = c >> 2, g = c & 3;
    ws[OFF_WIA + gid] = Wih_m[((size_t)g * 512 + j) * 1024 + k];
    return;
  }
  gid -= (size_t)2048 * 512;
  if (gid < 512) { ws[OFF_WEF + gid] = w_e[gid]; return; }
  gid -= 512;
  if (gid < 2048) { ws[OFF_BM + gid] = bih_m[gid] + bhh_m[gid]; return; }
  gid -= 2048;
  if (gid < (size_t)393216) { ws[OFF_HC_P + gid] = 0.f; return; }  // HC_P,HC_H,C_P,C_H
  gid -= 393216;
  if (gid < (size_t)131072) { ws[OFF_HM + gid] = 0.f; return; }    // HM, CM
  gid -= 131072;
  if (gid < 13824) { ws[OFF_BARP + gid] = 0.f; return; }           // ALL barrier slots
}

// ---------------- generic 64x64-tile fp32 GEMM (Ws = HS @ W_s^T) ----------------
__global__ __launch_bounds__(256) void k_gemm(const float* __restrict__ A,
                                              const float* __restrict__ Bw, int ldb, int Kdim,
                                              int N, float* __restrict__ C, int ntilesN) {
  __shared__ float As[16][68];
  __shared__ float Bs[16][68];
  const int tid = threadIdx.x;
  const int bid = blockIdx.x;
  const int tm = bid / ntilesN, tn = bid % ntilesN;
  const int m0 = tm * 64, n0 = tn * 64;
  const int tx = tid & 15, ty = tid >> 4;
  const int srow = tid >> 2, skc = (tid & 3) * 4;
  float acc[4][4] = {};
  const float* arowf = A + (size_t)(m0 + srow) * Kdim;
  const float* brow = Bw + (size_t)(n0 + srow) * ldb;
  for (int k0 = 0; k0 < Kdim; k0 += 16) {
    float4 v = *(const float4*)(arowf + k0 + skc);
    As[skc + 0][srow] = v.x; As[skc + 1][srow] = v.y;
    As[skc + 2][srow] = v.z; As[skc + 3][srow] = v.w;
#pragma unroll
    for (int i = 0; i < 4; i++) Bs[skc + i][srow] = brow[k0 + skc + i];
    __syncthreads();
#pragma unroll
    for (int kk = 0; kk < 16; kk++) {
      float4 a4 = *(float4*)&As[kk][ty * 4];
      float4 b4 = *(float4*)&Bs[kk][tx * 4];
      acc[0][0] += a4.x * b4.x; acc[0][1] += a4.x * b4.y; acc[0][2] += a4.x * b4.z; acc[0][3] += a4.x * b4.w;
      acc[1][0] += a4.y * b4.x; acc[1][1] += a4.y * b4.y; acc[1][2] += a4.y * b4.z; acc[1][3] += a4.y * b4.w;
      acc[2][0] += a4.z * b4.x; acc[2][1] += a4.z * b4.y; acc[2][2] += a4.z * b4.z; acc[2][3] += a4.z * b4.w;
      acc[3][0] += a4.w * b4.x; acc[3][1] += a4.w * b4.y; acc[3][2] += a4.w * b4.z; acc[3][3] += a4.w * b4.w;
    }
    __syncthreads();
  }
  const int m = m0 + ty * 4, n = n0 + tx * 4;
#pragma unroll
  for (int i = 0; i < 4; i++) {
    float4 o = {acc[i][0], acc[i][1], acc[i][2], acc[i][3]};
    *(float4*)&C[(size_t)(m + i) * N + n] = o;
  }
}

// ---------------- persistent LSTM: 256 blocks x 512 thr; 16-block domains; block-private xg ----
// Block (seq, gb, gj) owns 16 b x 128 packed-c. Whh from L2 (wave-uniform); h carry via atomics
// (32 KB/block/step); xg computed block-locally per 16-step window with PLAIN stores (128 KB slice).
// One 16-block domain barrier per step; NO window barrier.
__global__ __launch_bounds__(512) void k_lstm_mega(float* __restrict__ ws,
    const int* __restrict__ premise, const int* __restrict__ hyp,
    const int* __restrict__ plen, const int* __restrict__ hlen,
    const float* __restrict__ emb) {
  __shared__ float4 smem4[2048];           // 32 KB: step h-tile [16 b][128 k4] swizzled
  float* xAs = (float*)smem4;              // window: A [16 k][68]
  float* xBs = xAs + 16 * 68;              // window: B [16 k][68]
  int* xTok = (int*)(xBs + 16 * 68);       // window: 64 tokens

  const int tid = threadIdx.x;
  const int bid = blockIdx.x;
  const int seq = bid >> 7;
  const int u = bid & 127;
  const int gb = u >> 4, gj = u & 15;
  const int T = seq ? THh : TPp;
  const int* toks = seq ? hyp : premise;
  const int* lens = seq ? hlen : plen;
  const float* WL = ws + (seq ? OFF_WHHT_H : OFF_WHHT_P);   // [2048 c][512 k]
  const float* WXp = ws + (seq ? OFF_WIHT_H : OFF_WIHT_P);  // [304 k][2048 packed c]
  float* hc = ws + (seq ? OFF_HC_H : OFF_HC_P);
  float* hsout = ws + (seq ? OFF_HT : OFF_HS);
  float* xgb = ws + OFF_WSM + (size_t)bid * 32768;          // private [16 tl][16 bl][128 c]
  unsigned* bar = (unsigned*)(ws + (seq ? OFF_BARH : OFF_BARP)) + gb * 272;
  const int dfirst = seq * 128 + gb * 16;

  const int w = tid >> 6, lane = tid & 63;
  const int b_loc = lane & 15, kq = lane >> 4;
  const int b_glob = gb * 16 + b_loc;
  const int c0 = gj * 128 + w * 16;   // packed col base of this wave
  const int j0 = c0 >> 2;
  const int len = lens[b_glob];
  float c_r[4] = {0.f, 0.f, 0.f, 0.f}, h_r[4] = {0.f, 0.f, 0.f, 0.f};
  int ep = 1;

  for (int t = 0; t < T; t++) {
    if ((t & 15) == 0) {
      // ---- window: block-private xg GEMM, 8 tiles of 64 rows x 64 cols, K=304 ----
      __syncthreads();
      const int sr = tid & 63, sk2 = (tid >> 6) * 2;
      const int tx = tid & 15, ty = tid >> 4;  // ty 0..31
      for (int ti = 0; ti < 8; ti++) {
        const int m0 = (ti >> 1) * 64;          // row base (row = tl*16+bl)
        const int cb = (ti & 1) * 64;           // local packed-col base
        if (tid < 64) {
          int rr = m0 + tid;
          int tl = rr >> 4, bl = rr & 15;
          xTok[tid] = toks[(size_t)(gb * 16 + bl) * T + t + tl];
        }
        __syncthreads();
        float acc2[2][4] = {};
        for (int k0 = 0; k0 < 304; k0 += 16) {
          int tok = xTok[sr];
#pragma unroll
          for (int i = 0; i < 2; i++) {
            int kx = k0 + sk2 + i;
            float v = 0.f;
            if (kx < 300) v = emb[(size_t)tok * 300 + kx];
            else if (kx == 303) v = 1.0f;  // bias-one row
            xAs[(sk2 + i) * 68 + sr] = v;
          }
#pragma unroll
          for (int s = 0; s < 2; s++) {
            int i2 = tid + s * 512;
            int kb = i2 >> 6, nb = i2 & 63;
            xBs[kb * 68 + nb] = WXp[(size_t)(k0 + kb) * 2048 + gj * 128 + cb + nb];
          }
          __syncthreads();
#pragma unroll
          for (int kk = 0; kk < 16; kk++) {
            float a0 = xAs[kk * 68 + ty * 2];
            float a1 = xAs[kk * 68 + ty * 2 + 1];
            float4 b4 = *(float4*)&xBs[kk * 68 + tx * 4];
            acc2[0][0] += a0 * b4.x; acc2[0][1] += a0 * b4.y; acc2[0][2] += a0 * b4.z; acc2[0][3] += a0 * b4.w;
            acc2[1][0] += a1 * b4.x; acc2[1][1] += a1 * b4.y; acc2[1][2] += a1 * b4.z; acc2[1][3] += a1 * b4.w;
          }
          __syncthreads();
        }
#pragma unroll
        for (int i = 0; i < 2; i++) {
          int rr = m0 + ty * 2 + i;
          int tl = rr >> 4, bl = rr & 15;
          float4 o = {acc2[i][0], acc2[i][1], acc2[i][2], acc2[i][3]};
          *(float4*)&xgb[((size_t)tl * 16 + bl) * 128 + cb + tx * 4] = o;  // PLAIN store
        }
        __syncthreads();
      }
    }
    // ---- step t ----
    {
      const float* hin = hc + (size_t)(t & 1) * (BB * HH);
      float* hout = hc + (size_t)((t + 1) & 1) * (BB * HH);
#pragma unroll
      for (int i = 0; i < 4; i++) {
        int f = tid + 512 * i;
        int bl = f >> 7, k4 = f & 127;
        smem4[bl * 128 + (k4 ^ (bl & 7))] = aload16(hin + (size_t)(gb * 16 + bl) * 512 + k4 * 4);
      }
      __syncthreads();
      float acc[16];
#pragma unroll
      for (int c = 0; c < 16; c++) acc[c] = 0.f;
      for (int it = 0; it < 32; it++) {
        int kk = it * 16 + kq * 4;
        float4 a4 = smem4[b_loc * 128 + ((it * 4 + kq) ^ (b_loc & 7))];
#pragma unroll
        for (int cq = 0; cq < 16; cq++) {
          float4 w4 = *(const float4*)&WL[(size_t)(c0 + cq) * 512 + kk];
          acc[cq] += a4.x * w4.x + a4.y * w4.y + a4.z * w4.z + a4.w * w4.w;
        }
      }
#pragma unroll
      for (int cq = 0; cq < 16; cq++) acc[cq] = red4(acc[cq]);
      if (kq == 0) {
        const float* xb = xgb + ((size_t)(t & 15) * 16 + b_loc) * 128 + w * 16;
        float4 hv;
        float* hvp = (float*)&hv;
        bool inr = t < len;
#pragma unroll
        for (int jl = 0; jl < 4; jl++) {
          float4 xa = *(const float4*)(xb + jl * 4);   // PLAIN load (block-private)
          float iv = sigmf(acc[jl * 4 + 0] + xa.x);
          float fv = sigmf(acc[jl * 4 + 1] + xa.y);
          float gv = tanh_f(acc[jl * 4 + 2] + xa.z);
          float ov = sigmf(acc[jl * 4 + 3] + xa.w);
          float cn = fv * c_r[jl] + iv * gv;
          float hn = ov * tanh_f(cn);
          if (inr) { c_r[jl] = cn; h_r[jl] = hn; }
          hvp[jl] = inr ? hn : 0.f;
        }
        *(float4*)(hsout + ((size_t)b_glob * T + t) * 512 + j0) = hv;
        float4 ho = {h_r[0], h_r[1], h_r[2], h_r[3]};
        astore16(hout + (size_t)b_glob * 512 + j0, ho);
      }
      gbarD(bar, ep, dfirst, 16); ep++;
    }
  }
}

// ---------------- persistent match: 256 blocks x 512 thr; 8 independent 32-block stripes ----
__global__ __launch_bounds__(512) void k_match_mega(float* __restrict__ ws,
                                                    const int* __restrict__ hlen) {
  __shared__ float4 smem4[4096];  // 64 KB
  float4* A1 = smem4;             // P1: [16 r][256 k4] swz (64 KB)
  float4* A3 = smem4;             // P3: [16 r][128 k4] swz (32 KB)
  float* SC = (float*)smem4;      // P2 scratch

  const int tid = threadIdx.x;
  const int bid = blockIdx.x;
  const int gr = bid >> 5, gc = bid & 31;
  const int dfirst = gr * 32;
  unsigned* bar = (unsigned*)(ws + OFF_BARM) + gr * 528;

  float* hm = ws + OFF_HM;
  const float* ht = ws + OFF_HT;
  float* q = ws + OFF_Q;
  float* gh = ws + OFF_GH;
  float* abuf = ws + OFF_A;
  float* last = ws + OFF_LAST;
  const float* B1 = ws + OFF_WB1T;
  const float* W3 = ws + OFF_WIA;

  const int w = tid >> 6, lane = tid & 63;
  const int rl = lane & 15, kq = lane >> 4;
  const int r_g = gr * 16 + rl;
  const int c0p = gc * 80 + w * 10;   // P1 col base (packed 0..2559)
  const int c0q = gc * 64 + w * 8;    // P3 col base (packed 0..2047)
  const int jq = c0q >> 2;            // P3 first j (2 j per wave)
  float c_reg[2] = {0.f, 0.f};
  const int hl = hlen[r_g];
  float bmp[8];
#pragma unroll
  for (int jl = 0; jl < 2; jl++)
#pragma unroll
    for (int g = 0; g < 4; g++) bmp[jl * 4 + g] = ws[OFF_BM + g * 512 + jq + jl];
  int ep = 1;

  for (int k = 0; k < THh; k++) {
    // ---------- P1: q/gh rows of gr = [hm | ht_k] @ B1 cols [c0p..c0p+9] ----------
    {
#pragma unroll
      for (int i = 0; i < 8; i++) {
        int f = tid + 512 * i;
        int rr = f >> 8, k4 = f & 255;
        float4 v;
        if (k4 < 128) v = aload16(&hm[(size_t)(gr * 16 + rr) * 512 + k4 * 4]);
        else v = *(const float4*)&ht[((size_t)(gr * 16 + rr) * THh + k) * 512 + (k4 - 128) * 4];
        A1[rr * 256 + (k4 ^ (rr & 7))] = v;
      }
      __syncthreads();
      float acc[10];
#pragma unroll
      for (int cc = 0; cc < 10; cc++) acc[cc] = 0.f;
      for (int it = 0; it < 64; it++) {
        int kk = it * 16 + kq * 4;
        float4 a4 = A1[rl * 256 + ((it * 4 + kq) ^ (rl & 7))];
#pragma unroll
        for (int cc = 0; cc < 10; cc++) {
          float4 b4 = *(const float4*)&B1[(size_t)(c0p + cc) * 1024 + kk];
          acc[cc] += a4.x * b4.x + a4.y * b4.y + a4.z * b4.z + a4.w * b4.w;
        }
      }
#pragma unroll
      for (int cc = 0; cc < 10; cc++) acc[cc] = red4(acc[cc]);
      if (kq == 0) {
#pragma unroll
        for (int cc = 0; cc < 10; cc++) {
          int c = c0p + cc;
          if (c < 512) astore4(&q[(size_t)r_g * 512 + c], acc[cc]);
          else astore4(&gh[(size_t)r_g * 2048 + (c - 512)], acc[cc]);
        }
      }
    }
    gbarD(bar, ep, dfirst, 32); ep++;
    // ---------- P2: attention for row b = gr*16+gc (blocks gc<16) ----------
    if (gc < 16) {
      const int b = gr * 16 + gc;
      float* q_lds = SC; float* we_lds = SC + 512; float* e_part = SC + 1024;
      float* e_lds = SC + 1536; float* alpha_lds = SC + 1664; float* red_s = SC + 1792;
      const float* Wsb = ws + OFF_WSM;
      const float* hs = ws + OFF_HS;
      q_lds[tid] = aload4(&q[(size_t)b * 512 + tid]);
      we_lds[tid] = ws[OFF_WEF + tid];
      __syncthreads();
      {
        int t2 = tid >> 2;
        int gbase = (tid & 3) * 128;
        const float* wsrow = Wsb + ((size_t)b * TPp + t2) * 512 + gbase;
        float s = 0.f;
        for (int ii = 0; ii < 128; ii += 4) {
          float4 wv = *(const float4*)(wsrow + ii);
          float4 qv = *(float4*)&q_lds[gbase + ii];
          float4 ev = *(float4*)&we_lds[gbase + ii];
          s += tanh_f(wv.x + qv.x) * ev.x + tanh_f(wv.y + qv.y) * ev.y +
               tanh_f(wv.z + qv.z) * ev.z + tanh_f(wv.w + qv.w) * ev.w;
        }
        e_part[tid] = s;
      }
      __syncthreads();
      if (tid < 128)
        e_lds[tid] = e_part[tid * 4] + e_part[tid * 4 + 1] + e_part[tid * 4 + 2] + e_part[tid * 4 + 3];
      __syncthreads();
      if (tid < 64) {
        float m = fmaxf(e_lds[tid], e_lds[tid + 64]);
        for (int off = 32; off > 0; off >>= 1) m = fmaxf(m, __shfl_down(m, off));
        if (tid == 0) red_s[0] = m;
      }
      __syncthreads();
      if (tid < 128) alpha_lds[tid] = __expf(e_lds[tid] - red_s[0]);
      __syncthreads();
      if (tid < 64) {
        float s = alpha_lds[tid] + alpha_lds[tid + 64];
        for (int off = 32; off > 0; off >>= 1) s += __shfl_down(s, off);
        if (tid == 0) red_s[1] = 1.f / s;
      }
      __syncthreads();
      {
        float inv = red_s[1];
        float a0 = 0.f;
        const float* hsb = hs + (size_t)b * TPp * 512 + tid;
        for (int t2 = 0; t2 < TPp; t2++) a0 += alpha_lds[t2] * hsb[(size_t)t2 * 512];
        astore4(&abuf[(size_t)b * 512 + tid], a0 * inv);
      }
    }
    gbarD(bar, ep, dfirst, 32); ep++;
    // ---------- P3: cell update for rows of gr, j in [gc*16, gc*16+16) ----------
    {
#pragma unroll
      for (int i = 0; i < 4; i++) {
        int f = tid + 512 * i;
        int rr = f >> 7, k4 = f & 127;
        A3[rr * 128 + (k4 ^ (rr & 7))] = aload16(&abuf[(size_t)(gr * 16 + rr) * 512 + k4 * 4]);
      }
      __syncthreads();
      float acc[8];
#pragma unroll
      for (int cc = 0; cc < 8; cc++) acc[cc] = 0.f;
      for (int it = 0; it < 32; it++) {
        int kk = it * 16 + kq * 4;
        float4 a4 = A3[rl * 128 + ((it * 4 + kq) ^ (rl & 7))];
#pragma unroll
        for (int cc = 0; cc < 8; cc++) {
          float4 w4 = *(const float4*)&W3[(size_t)(c0q + cc) * 512 + kk];
          acc[cc] += a4.x * w4.x + a4.y * w4.y + a4.z * w4.z + a4.w * w4.w;
        }
      }
#pragma unroll
      for (int cc = 0; cc < 8; cc++) acc[cc] = red4(acc[cc]);
      if (kq == 0) {
#pragma unroll
        for (int jl = 0; jl < 2; jl++) {
          float4 gh4 = aload16(&gh[(size_t)r_g * 2048 + c0q + jl * 4]);
          float iv = sigmf(acc[jl * 4 + 0] + gh4.x + bmp[jl * 4 + 0]);
          float fv = sigmf(acc[jl * 4 + 1] + gh4.y + bmp[jl * 4 + 1]);
          float gv = tanh_f(acc[jl * 4 + 2] + gh4.z + bmp[jl * 4 + 2]);
          float ov = sigmf(acc[jl * 4 + 3] + gh4.w + bmp[jl * 4 + 3]);
          float cn = fv * c_reg[jl] + iv * gv;
          float hn = ov * tanh_f(cn);
          c_reg[jl] = cn;
          astore4(&hm[(size_t)r_g * 512 + jq + jl], hn);
          if (k == hl - 1) last[(size_t)r_g * 512 + jq + jl] = hn;
        }
      }
    }
    gbarD(bar, ep, dfirst, 32); ep++;
  }
}

// ---------------- FC epilogue ----------------
__global__ __launch_bounds__(256) void k_fc(const float* __restrict__ ws, const float* __restrict__ Wfc,
                                            const float* __restrict__ bfc, float* __restrict__ out) {
  int idx = blockIdx.x * 256 + threadIdx.x;
  if (idx >= BB * 3) return;
  int b = idx / 3, o = idx - b * 3;
  const float* lrow = ws + OFF_LAST + (size_t)b * 512;
  const float* wrow = Wfc + (size_t)o * 512;
  float acc = bfc[o];
  for (int h = 0; h < 512; h++) acc += lrow[h] * wrow[h];
  out[idx] = acc;
}

extern "C" void kernel_launch(void* const* d_in, const int* in_sizes, int n_in, void* d_out,
                              int out_size, void* d_ws, size_t ws_size, hipStream_t stream) {
  const int* premise = (const int*)d_in[0];
  const int* plen = (const int*)d_in[1];
  const int* hyp = (const int*)d_in[2];
  const int* hlen = (const int*)d_in[3];
  const float* emb = (const float*)d_in[4];
  const float* Wih_p = (const float*)d_in[5];
  const float* Whh_p = (const float*)d_in[6];
  const float* bih_p = (const float*)d_in[7];
  const float* bhh_p = (const float*)d_in[8];
  const float* Wih_h = (const float*)d_in[9];
  const float* Whh_h = (const float*)d_in[10];
  const float* bih_h = (const float*)d_in[11];
  const float* bhh_h = (const float*)d_in[12];
  const float* Wih_m = (const float*)d_in[13];
  const float* Whh_m = (const float*)d_in[14];
  const float* bih_m = (const float*)d_in[15];
  const float* bhh_m = (const float*)d_in[16];
  const float* w_e = (const float*)d_in[17];
  const float* W_s = (const float*)d_in[18];
  const float* W_t = (const float*)d_in[19];
  const float* W_m = (const float*)d_in[20];
  const float* W_fc = (const float*)d_in[21];
  const float* b_fc = (const float*)d_in[22];
  float* ws = (float*)d_ws;
  float* out = (float*)d_out;

  if (ws_size < WS_FLOATS * sizeof(float)) {
    float mb = (float)((double)ws_size / (1024.0 * 1024.0));
    k_diag<<<dim3(6), dim3(64), 0, stream>>>(out, mb);
    return;
  }

  // K0: weight prep + state/slot zero
  {
    size_t total = 2 * SZ_WIHT + 2 * (size_t)512 * 2048 + (size_t)2560 * 1024 +
                   (size_t)2048 * 512 + 512 + 2048 + 393216 + 131072 + 13824;
    int nb = (int)((total + 255) / 256);
    k_prep<<<dim3(nb), dim3(256), 0, stream>>>(ws, Wih_p, bih_p, bhh_p, Wih_h, bih_h, bhh_h,
                                               Whh_p, Whh_h, Whh_m, Wih_m, bih_m, bhh_m,
                                               W_m, W_t, w_e);
  }
  // persistent LSTM (16 independent 16-block domains, block-private xg, 1 barrier/step)
  {
    void* args[] = {(void*)&ws, (void*)&premise, (void*)&hyp, (void*)&plen, (void*)&hlen, (void*)&emb};
    hipError_t e = hipLaunchCooperativeKernel((const void*)k_lstm_mega, dim3(256), dim3(512),
                                              args, 0, stream);
    if (e != hipSuccess)
      k_lstm_mega<<<dim3(256), dim3(512), 0, stream>>>(ws, premise, hyp, plen, hlen, emb);
  }
  // Ws = HS @ W_s^T (WSM region free again)
  k_gemm<<<dim3(256 * 8), dim3(256), 0, stream>>>(ws + OFF_HS, W_s, 512, 512, 512,
                                                  ws + OFF_WSM, 8);
  // persistent match loop (8 independent 32-block stripes, 3 domain barriers/step)
  {
    void* args[] = {(void*)&ws, (void*)&hlen};
    hipError_t e = hipLaunchCooperativeKernel((const void*)k_match_mega, dim3(256), dim3(512),
                                              args, 0, stream);
    if (e != hipSuccess)
      k_match_mega<<<dim3(256), dim3(512), 0, stream>>>(ws, hlen);
  }
  // FC epilogue
  k_fc<<<dim3(2), dim3(256), 0, stream>>>(ws, W_fc, b_fc, out);
}